// Round 16
// baseline (130.479 us; speedup 1.0000x reference)
//
#include <hip/hip_runtime.h>

#define NV 12
#define CIN 384
#define COUT 32
#define HW 4096        // 64*64 feature pixels
#define NVOX 262144    // 64^3 voxels
#define KSTEPS 12      // 384 / 32
#define KSTEP 32
#define PIXB 256       // pixels per block (8 waves x 2 x 16)
#define ZROW_U4 786432 // uint4 index of the 64B zero row (= 48*4096*32 bf16 / 8)

typedef __attribute__((ext_vector_type(8))) short short8v;   // 8 bf16 (4 VGPR)
typedef __attribute__((ext_vector_type(4))) float f32x4;     // MFMA accum

// fp32 -> bf16 bits, round-to-nearest-even (finite data; NaN not handled).
__device__ __forceinline__ short bf16b(float x) {
    union { float f; unsigned u; } c; c.f = x;
    unsigned r = (c.u + 0x7fffu + ((c.u >> 16) & 1u)) >> 16;
    return (short)r;
}

// Async global->LDS DMA, 16B per lane (dest = uniform base + lane*16).
__device__ __forceinline__ void load_lds16(const float* g, float* l) {
    __builtin_amdgcn_global_load_lds(
        (const __attribute__((address_space(1))) void*)g,
        (__attribute__((address_space(3))) void*)l, 16, 0, 0);
}

// Prep: repack W into MFMA A-fragment order (bf16) + zero the fuse zero-row.
__global__ __launch_bounds__(256) void w_prep_kernel(
    const float* __restrict__ w, short* __restrict__ wfrag,
    short* __restrict__ feats)
{
    const int t = blockIdx.x * 256 + threadIdx.x;
    if (t < 48 * 32) {
        const int sg = t >> 5, o = t & 31;
        const int s = sg >> 2, g = sg & 3;
        short8v v;
#pragma unroll
        for (int i = 0; i < 8; ++i)
            v[i] = bf16b(w[o * CIN + s * 32 + g * 8 + i]);
        *reinterpret_cast<short8v*>(wfrag + t * 8) = v;
    } else if (t >= 1536 && t < 1540) {
        reinterpret_cast<uint4*>(feats)[ZROW_U4 + (t - 1536)] =
            make_uint4(0u, 0u, 0u, 0u);
    }
}

// Kernel 1: channel reduce 384->32, MFMA, DMA-staged.
// R16 (deconfounded R14): every global_load_lds covers 1KB FULLY CONTIGUOUS
// and 1KB-page-aligned (one whole 256-pix row segment = exactly one HBM page;
// fixes the 50% row-buffer efficiency of R11's 512B chunks at 16KB stride)
// while KEEPING 24 waves/CU (512-thread blocks, 3 blocks/CU x 8 waves —
// R14's regression was the occupancy drop, not the chunk size).
// Wave w stages rows 4w..4w+3; computes pixel tiles 32w, 32w+16.
// Rotation: row r stored with pixel P at col (P + 8*(r>>3)) & 255 via source
// chunk (l - 2*(w>>1)) & 63; reader col (pix + 8g) & 255 -> 2-way banks, free.
__global__ __launch_bounds__(512) void mv_reduce_mfma_kernel(
    const float* __restrict__ vit, const short* __restrict__ wfrag,
    const float* __restrict__ bias, short* __restrict__ feats)
{
    __shared__ float lds[KSTEP][PIXB];       // 32 KB

    const int bid  = blockIdx.x;             // 0..767
    const int bv   = bid >> 4;               // 0..47
    const int pix0 = (bid & 15) * PIXB;

    const int tid  = threadIdx.x;
    const int wave = tid >> 6;               // 0..7
    const int l    = tid & 63;
    const int col  = l & 15;                 // pixel-in-tile / o-in-tile
    const int g    = l >> 4;                 // k-group
    const int srcq = (l - 2 * (wave >> 1)) & 63;  // rotated source chunk

    const float* vbase = vit + (size_t)bv * CIN * HW + pix0;
    const short8v* wf  = reinterpret_cast<const short8v*>(wfrag);

    // Reader columns: pixel tiles 32w and 32w+16, rotated +8g.
    const int rc0 = (wave * 32 + col + 8 * g) & 255;
    const int rc1 = (wave * 32 + 16 + col + 8 * g) & 255;

    f32x4 acc00 = {0.f, 0.f, 0.f, 0.f};
    f32x4 acc01 = {0.f, 0.f, 0.f, 0.f};
    f32x4 acc10 = {0.f, 0.f, 0.f, 0.f};
    f32x4 acc11 = {0.f, 0.f, 0.f, 0.f};

#define STAGE(s)                                                           \
    {                                                                      \
        _Pragma("unroll")                                                  \
        for (int j_ = 0; j_ < 4; ++j_) {                                   \
            const int row_ = 4 * wave + j_;                                \
            load_lds16(vbase + (size_t)((s) * KSTEP + row_) * HW           \
                           + srcq * 4,                                     \
                       &lds[row_][0]);                                     \
        }                                                                  \
    }

    STAGE(0)

#pragma unroll
    for (int s = 0; s < KSTEPS; ++s) {
        __syncthreads();                     // vmcnt(0): DMA(s) landed

        float fr0[8], fr1[8];
#pragma unroll
        for (int i = 0; i < 8; ++i) {
            fr0[i] = lds[8 * g + i][rc0];
            fr1[i] = lds[8 * g + i][rc1];
        }
        __syncthreads();                     // reads done; LDS reusable

        if (s + 1 < KSTEPS) STAGE(s + 1)     // 1KB/page/inst, flies over compute

        short8v bfr0, bfr1;
#pragma unroll
        for (int i = 0; i < 8; ++i) {
            bfr0[i] = bf16b(fr0[i]);
            bfr1[i] = bf16b(fr1[i]);
        }

        const short8v a0 = wf[(s * 4 + g) * 32 + col];        // o = col
        const short8v a1 = wf[(s * 4 + g) * 32 + 16 + col];   // o = 16 + col

        acc00 = __builtin_amdgcn_mfma_f32_16x16x32_bf16(a0, bfr0, acc00, 0, 0, 0);
        acc01 = __builtin_amdgcn_mfma_f32_16x16x32_bf16(a1, bfr0, acc01, 0, 0, 0);
        acc10 = __builtin_amdgcn_mfma_f32_16x16x32_bf16(a0, bfr1, acc10, 0, 0, 0);
        acc11 = __builtin_amdgcn_mfma_f32_16x16x32_bf16(a1, bfr1, acc11, 0, 0, 0);
    }
#undef STAGE

    // Store bf16, permuted row (R15): lane (col,g) emits one 16B store per
    // pixel-tile; wave-inst covers 16 full 64B lines.
    const float4 b0 = *reinterpret_cast<const float4*>(bias + 4 * g);
    const float4 b1 = *reinterpret_cast<const float4*>(bias + 16 + 4 * g);
    short* dst0 = feats + ((size_t)bv * HW + pix0 + wave * 32 + col) * COUT + 8 * g;
    short* dst1 = dst0 + 16 * COUT;
    short8v ov0, ov1;
    ov0[0] = bf16b(acc00[0] + b0.x); ov0[1] = bf16b(acc00[1] + b0.y);
    ov0[2] = bf16b(acc00[2] + b0.z); ov0[3] = bf16b(acc00[3] + b0.w);
    ov0[4] = bf16b(acc01[0] + b1.x); ov0[5] = bf16b(acc01[1] + b1.y);
    ov0[6] = bf16b(acc01[2] + b1.z); ov0[7] = bf16b(acc01[3] + b1.w);
    ov1[0] = bf16b(acc10[0] + b0.x); ov1[1] = bf16b(acc10[1] + b0.y);
    ov1[2] = bf16b(acc10[2] + b0.z); ov1[3] = bf16b(acc10[3] + b0.w);
    ov1[4] = bf16b(acc11[0] + b1.x); ov1[5] = bf16b(acc11[1] + b1.y);
    ov1[6] = bf16b(acc11[2] + b1.z); ov1[7] = bf16b(acc11[3] + b1.w);
    *reinterpret_cast<short8v*>(dst0) = ov0;
    *reinterpret_cast<short8v*>(dst1) = ov1;
}

// Kernel 2: fuse, 4 lanes per voxel (R15 form, unchanged).
// Chunk r holds channels {4r..4r+3, 16+4r..16+4r+3} (permuted feats row).
__global__ __launch_bounds__(256) void mv_fuse_kernel(
    const unsigned short* __restrict__ feats, const float* __restrict__ proj,
    float* __restrict__ out)
{
    __shared__ double P[NV][12];

    const int tid = threadIdx.x;
    const unsigned gid = blockIdx.x * 256u + tid;
    const unsigned vox = gid >> 2;          // voxel id = b*NVOX + n
    const int r = tid & 3;                  // chunk index within group
    const int lane = tid & 63;
    const int b = vox >> 18;
    const int n = vox & (NVOX - 1);

    if (tid < NV * 12) {
        const int v = tid / 12, e = tid - v * 12;
        const int row = e >> 2;
        const float s = (row < 2) ? 0.25f : 1.0f;   // projection[:,:, :2,:]/STRIDE
        P[v][e] = (double)(proj[((b * NV + v) * 3 + row) * 4 + (e & 3)] * s);
    }
    __syncthreads();

    const int k = n & 63, j = (n >> 6) & 63, i = n >> 12;
    const double wx = (double)i * 0.04 - 1.28;
    const double wy = (double)j * 0.04 - 1.28;
    const double wz = (double)k * 0.04 - 1.28;

    // Phase 1: this lane's 3 views (v = 4s + r).
    int off[3];
    int cnt = 0;
    const int bbase = b * (NV * HW * 4);
#pragma unroll
    for (int s = 0; s < 3; ++s) {
        const double* p = P[4 * s + r];
        const double cz = p[8] * wx + p[9] * wy + p[10] * wz + p[11];
        const double cx = p[0] * wx + p[1] * wy + p[2] * wz + p[3];
        const double cy = p[4] * wx + p[5] * wy + p[6] * wz + p[7];
        const double rcz = 1.0 / cz;
        const double u = rint(cx * rcz);   // round-half-even == jnp.round
        const double t = rint(cy * rcz);
        const bool valid = (cz > 0.0) & (u >= 0.0) & (u <= 63.0) &
                           (t >= 0.0) & (t <= 63.0);
        const double uc = fmin(fmax(u, 0.0), 63.0);
        const double tc = fmin(fmax(t, 0.0), 63.0);
        const int pix = (int)uc + 64 * (int)tc;
        off[s] = valid ? (bbase + ((4 * s + r) * HW + pix) * 4) : ZROW_U4;
        cnt += valid ? 1 : 0;
    }
    cnt += __shfl_xor(cnt, 1);
    cnt += __shfl_xor(cnt, 2);              // group-total valid count

    // Phase 2: gather + accumulate.
    float acc[8];
#pragma unroll
    for (int q = 0; q < 8; ++q) acc[q] = 0.0f;

    const uint4* f4 = reinterpret_cast<const uint4*>(feats);
#pragma unroll
    for (int v = 0; v < NV; ++v) {
        const int src = (lane & ~3) | (v & 3);      // owner lane of view v
        const int ov = __shfl(off[v >> 2], src, 64);
        const uint4 u4 = f4[ov + r];
        acc[0] += __uint_as_float(u4.x << 16);
        acc[1] += __uint_as_float(u4.x & 0xffff0000u);
        acc[2] += __uint_as_float(u4.y << 16);
        acc[3] += __uint_as_float(u4.y & 0xffff0000u);
        acc[4] += __uint_as_float(u4.z << 16);
        acc[5] += __uint_as_float(u4.z & 0xffff0000u);
        acc[6] += __uint_as_float(u4.w << 16);
        acc[7] += __uint_as_float(u4.w & 0xffff0000u);
    }

    const float sc = (cnt > 0) ? (1.0f / (float)cnt) : 0.0f;
    float* ob0 = out + (size_t)b * COUT * NVOX + (size_t)(4 * r) * NVOX + n;
    float* ob1 = ob0 + (size_t)16 * NVOX;
#pragma unroll
    for (int q = 0; q < 4; ++q) {
        ob0[(size_t)q * NVOX] = acc[q] * sc;
        ob1[(size_t)q * NVOX] = acc[4 + q] * sc;
    }
}

extern "C" void kernel_launch(void* const* d_in, const int* in_sizes, int n_in,
                              void* d_out, int out_size, void* d_ws, size_t ws_size,
                              hipStream_t stream) {
    const float* vit  = (const float*)d_in[0];  // (4,12,384,64,64)
    const float* w    = (const float*)d_in[1];  // (32,384)
    const float* bias = (const float*)d_in[2];  // (32,)
    const float* proj = (const float*)d_in[3];  // (4,12,3,4)
    float* out = (float*)d_out;                 // (4,32,64,64,64)

    short* wfrag = (short*)d_ws;                            // 24 KB
    short* feats = (short*)((char*)d_ws + 48 * 32 * 8 * 2); // bf16 12.6 MB + 64B zero row

    w_prep_kernel<<<7, 256, 0, stream>>>(w, wfrag, feats);

    mv_reduce_mfma_kernel<<<768, 512, 0, stream>>>(vit, wfrag, bias, feats);

    mv_fuse_kernel<<<16384, 256, 0, stream>>>(
        (const unsigned short*)feats, proj, out);
}

// Round 17
// 124.922 us; speedup vs baseline: 1.0445x; 1.0445x over previous
//
#include <hip/hip_runtime.h>

#define NV 12
#define CIN 384
#define COUT 32
#define HW 4096        // 64*64 feature pixels
#define NVOX 262144    // 64^3 voxels
#define KSTEPS 12      // 384 / 32
#define KSTEP 32
#define PIXB 128       // pixels per block (R11/R15 config — best known)
#define ZROW_U4 786432 // uint4 index of the 64B zero row (= 48*4096*32 bf16 / 8)

typedef __attribute__((ext_vector_type(8))) short short8v;   // 8 bf16 (4 VGPR)
typedef __attribute__((ext_vector_type(4))) float f32x4;     // MFMA accum

// fp32 -> bf16 bits, round-to-nearest-even (finite data; NaN not handled).
__device__ __forceinline__ short bf16b(float x) {
    union { float f; unsigned u; } c; c.f = x;
    unsigned r = (c.u + 0x7fffu + ((c.u >> 16) & 1u)) >> 16;
    return (short)r;
}

// Async global->LDS DMA, 16B per lane (dest = uniform base + lane*16).
__device__ __forceinline__ void load_lds16(const float* g, float* l) {
    __builtin_amdgcn_global_load_lds(
        (const __attribute__((address_space(1))) void*)g,
        (__attribute__((address_space(3))) void*)l, 16, 0, 0);
}

// Prep: repack W into MFMA A-fragment order (bf16) + zero the fuse zero-row.
__global__ __launch_bounds__(256) void w_prep_kernel(
    const float* __restrict__ w, short* __restrict__ wfrag,
    short* __restrict__ feats)
{
    const int t = blockIdx.x * 256 + threadIdx.x;
    if (t < 48 * 32) {
        const int sg = t >> 5, o = t & 31;
        const int s = sg >> 2, g = sg & 3;
        short8v v;
#pragma unroll
        for (int i = 0; i < 8; ++i)
            v[i] = bf16b(w[o * CIN + s * 32 + g * 8 + i]);
        *reinterpret_cast<short8v*>(wfrag + t * 8) = v;
    } else if (t >= 1536 && t < 1540) {
        reinterpret_cast<uint4*>(feats)[ZROW_U4 + (t - 1536)] =
            make_uint4(0u, 0u, 0u, 0u);
    }
}

// Kernel 1: channel reduce 384->32 (R11 structure: DMA-staged, 128-pix tile,
// rotated source chunks, 6 blocks/CU) with R15's permuted coalesced store.
// Final form — ledger R7-R16: barrier structure, LDS op count, issue order,
// pipeline depth/counted-vmcnt, chunk contiguity (512B/1KB), page alignment,
// occupancy (3/6/12 blk/CU) all measured null or negative; ~75us = 4.0 TB/s
// effective streaming is this pattern's practical ceiling on MI355X.
__global__ __launch_bounds__(256) void mv_reduce_mfma_kernel(
    const float* __restrict__ vit, const short* __restrict__ wfrag,
    const float* __restrict__ bias, short* __restrict__ feats)
{
    __shared__ float lds[KSTEP][PIXB];       // 16 KB

    const int bid  = blockIdx.x;             // 0..1535
    const int bv   = bid >> 5;               // 0..47
    const int pix0 = (bid & 31) * PIXB;

    const int tid  = threadIdx.x;
    const int wave = tid >> 6;               // 0..3
    const int l    = tid & 63;
    const int col  = l & 15;                 // pixel-in-tile / o-in-tile
    const int g    = l >> 4;                 // k-group
    const int lhalf = l >> 5;                // k-row within a DMA inst
    const int lq    = l & 31;                // 16B chunk within the row
    const int srcq  = (lq - 2 * wave) & 31;  // rotated source chunk

    const float* vbase = vit + (size_t)bv * CIN * HW + pix0;
    const short8v* wf  = reinterpret_cast<const short8v*>(wfrag);

    // Reader columns (rotation): row 8g+i holds pixel P at col (P + 8g) & 127.
    const int rc0 = (wave * 32 + col + 8 * g) & 127;
    const int rc1 = (wave * 32 + col + 16 + 8 * g) & 127;

    f32x4 acc00 = {0.f, 0.f, 0.f, 0.f};
    f32x4 acc01 = {0.f, 0.f, 0.f, 0.f};
    f32x4 acc10 = {0.f, 0.f, 0.f, 0.f};
    f32x4 acc11 = {0.f, 0.f, 0.f, 0.f};

#define STAGE(s)                                                           \
    {                                                                      \
        _Pragma("unroll")                                                  \
        for (int i_ = 0; i_ < 4; ++i_) {                                   \
            const int row_ = 8 * wave + 2 * i_;                            \
            load_lds16(vbase + (size_t)((s) * KSTEP + row_ + lhalf) * HW   \
                           + srcq * 4,                                     \
                       &lds[row_][0]);                                     \
        }                                                                  \
    }

    STAGE(0)

#pragma unroll
    for (int s = 0; s < KSTEPS; ++s) {
        __syncthreads();                     // vmcnt(0): DMA(s) landed

        float fr0[8], fr1[8];
#pragma unroll
        for (int i = 0; i < 8; ++i) {
            fr0[i] = lds[8 * g + i][rc0];
            fr1[i] = lds[8 * g + i][rc1];
        }
        __syncthreads();                     // reads done; LDS reusable

        if (s + 1 < KSTEPS) STAGE(s + 1)     // flies over compute below

        short8v bfr0, bfr1;
#pragma unroll
        for (int i = 0; i < 8; ++i) {
            bfr0[i] = bf16b(fr0[i]);
            bfr1[i] = bf16b(fr1[i]);
        }

        const short8v a0 = wf[(s * 4 + g) * 32 + col];        // o = col
        const short8v a1 = wf[(s * 4 + g) * 32 + 16 + col];   // o = 16 + col

        acc00 = __builtin_amdgcn_mfma_f32_16x16x32_bf16(a0, bfr0, acc00, 0, 0, 0);
        acc01 = __builtin_amdgcn_mfma_f32_16x16x32_bf16(a1, bfr0, acc01, 0, 0, 0);
        acc10 = __builtin_amdgcn_mfma_f32_16x16x32_bf16(a0, bfr1, acc10, 0, 0, 0);
        acc11 = __builtin_amdgcn_mfma_f32_16x16x32_bf16(a1, bfr1, acc11, 0, 0, 0);
    }
#undef STAGE

    // Store bf16, PERMUTED row: chunk g of each 64B pixel-row = channels
    // {4g..4g+3, 16+4g..16+4g+3}; one 16B store per pixel-tile -> wave-inst
    // covers 16 full 64B lines (fixes R13's measured 4.8x write amp).
    const float4 b0 = *reinterpret_cast<const float4*>(bias + 4 * g);
    const float4 b1 = *reinterpret_cast<const float4*>(bias + 16 + 4 * g);
    short* dst0 = feats + ((size_t)bv * HW + pix0 + wave * 32 + col) * COUT + 8 * g;
    short* dst1 = dst0 + 16 * COUT;
    short8v ov0, ov1;
    ov0[0] = bf16b(acc00[0] + b0.x); ov0[1] = bf16b(acc00[1] + b0.y);
    ov0[2] = bf16b(acc00[2] + b0.z); ov0[3] = bf16b(acc00[3] + b0.w);
    ov0[4] = bf16b(acc01[0] + b1.x); ov0[5] = bf16b(acc01[1] + b1.y);
    ov0[6] = bf16b(acc01[2] + b1.z); ov0[7] = bf16b(acc01[3] + b1.w);
    ov1[0] = bf16b(acc10[0] + b0.x); ov1[1] = bf16b(acc10[1] + b0.y);
    ov1[2] = bf16b(acc10[2] + b0.z); ov1[3] = bf16b(acc10[3] + b0.w);
    ov1[4] = bf16b(acc11[0] + b1.x); ov1[5] = bf16b(acc11[1] + b1.y);
    ov1[6] = bf16b(acc11[2] + b1.z); ov1[7] = bf16b(acc11[3] + b1.w);
    *reinterpret_cast<short8v*>(dst0) = ov0;
    *reinterpret_cast<short8v*>(dst1) = ov1;
}

// Kernel 2: fuse, 4 lanes per voxel (R15 form, unchanged).
// Chunk r holds channels {4r..4r+3, 16+4r..16+4r+3} (permuted feats row).
__global__ __launch_bounds__(256) void mv_fuse_kernel(
    const unsigned short* __restrict__ feats, const float* __restrict__ proj,
    float* __restrict__ out)
{
    __shared__ double P[NV][12];

    const int tid = threadIdx.x;
    const unsigned gid = blockIdx.x * 256u + tid;
    const unsigned vox = gid >> 2;          // voxel id = b*NVOX + n
    const int r = tid & 3;                  // chunk index within group
    const int lane = tid & 63;
    const int b = vox >> 18;
    const int n = vox & (NVOX - 1);

    if (tid < NV * 12) {
        const int v = tid / 12, e = tid - v * 12;
        const int row = e >> 2;
        const float s = (row < 2) ? 0.25f : 1.0f;   // projection[:,:, :2,:]/STRIDE
        P[v][e] = (double)(proj[((b * NV + v) * 3 + row) * 4 + (e & 3)] * s);
    }
    __syncthreads();

    const int k = n & 63, j = (n >> 6) & 63, i = n >> 12;
    const double wx = (double)i * 0.04 - 1.28;
    const double wy = (double)j * 0.04 - 1.28;
    const double wz = (double)k * 0.04 - 1.28;

    // Phase 1: this lane's 3 views (v = 4s + r).
    int off[3];
    int cnt = 0;
    const int bbase = b * (NV * HW * 4);
#pragma unroll
    for (int s = 0; s < 3; ++s) {
        const double* p = P[4 * s + r];
        const double cz = p[8] * wx + p[9] * wy + p[10] * wz + p[11];
        const double cx = p[0] * wx + p[1] * wy + p[2] * wz + p[3];
        const double cy = p[4] * wx + p[5] * wy + p[6] * wz + p[7];
        const double rcz = 1.0 / cz;
        const double u = rint(cx * rcz);   // round-half-even == jnp.round
        const double t = rint(cy * rcz);
        const bool valid = (cz > 0.0) & (u >= 0.0) & (u <= 63.0) &
                           (t >= 0.0) & (t <= 63.0);
        const double uc = fmin(fmax(u, 0.0), 63.0);
        const double tc = fmin(fmax(t, 0.0), 63.0);
        const int pix = (int)uc + 64 * (int)tc;
        off[s] = valid ? (bbase + ((4 * s + r) * HW + pix) * 4) : ZROW_U4;
        cnt += valid ? 1 : 0;
    }
    cnt += __shfl_xor(cnt, 1);
    cnt += __shfl_xor(cnt, 2);              // group-total valid count

    // Phase 2: gather + accumulate.
    float acc[8];
#pragma unroll
    for (int q = 0; q < 8; ++q) acc[q] = 0.0f;

    const uint4* f4 = reinterpret_cast<const uint4*>(feats);
#pragma unroll
    for (int v = 0; v < NV; ++v) {
        const int src = (lane & ~3) | (v & 3);      // owner lane of view v
        const int ov = __shfl(off[v >> 2], src, 64);
        const uint4 u4 = f4[ov + r];
        acc[0] += __uint_as_float(u4.x << 16);
        acc[1] += __uint_as_float(u4.x & 0xffff0000u);
        acc[2] += __uint_as_float(u4.y << 16);
        acc[3] += __uint_as_float(u4.y & 0xffff0000u);
        acc[4] += __uint_as_float(u4.z << 16);
        acc[5] += __uint_as_float(u4.z & 0xffff0000u);
        acc[6] += __uint_as_float(u4.w << 16);
        acc[7] += __uint_as_float(u4.w & 0xffff0000u);
    }

    const float sc = (cnt > 0) ? (1.0f / (float)cnt) : 0.0f;
    float* ob0 = out + (size_t)b * COUT * NVOX + (size_t)(4 * r) * NVOX + n;
    float* ob1 = ob0 + (size_t)16 * NVOX;
#pragma unroll
    for (int q = 0; q < 4; ++q) {
        ob0[(size_t)q * NVOX] = acc[q] * sc;
        ob1[(size_t)q * NVOX] = acc[4 + q] * sc;
    }
}

extern "C" void kernel_launch(void* const* d_in, const int* in_sizes, int n_in,
                              void* d_out, int out_size, void* d_ws, size_t ws_size,
                              hipStream_t stream) {
    const float* vit  = (const float*)d_in[0];  // (4,12,384,64,64)
    const float* w    = (const float*)d_in[1];  // (32,384)
    const float* bias = (const float*)d_in[2];  // (32,)
    const float* proj = (const float*)d_in[3];  // (4,12,3,4)
    float* out = (float*)d_out;                 // (4,32,64,64,64)

    short* wfrag = (short*)d_ws;                            // 24 KB
    short* feats = (short*)((char*)d_ws + 48 * 32 * 8 * 2); // bf16 12.6 MB + 64B zero row

    w_prep_kernel<<<7, 256, 0, stream>>>(w, wfrag, feats);

    mv_reduce_mfma_kernel<<<1536, 256, 0, stream>>>(vit, wfrag, bias, feats);

    mv_fuse_kernel<<<16384, 256, 0, stream>>>(
        (const unsigned short*)feats, proj, out);
}